// Round 3
// baseline (150.206 us; speedup 1.0000x reference)
//
#include <hip/hip_runtime.h>
#include <hip/hip_bf16.h>
#include <math.h>

#define N 8192
#define D 64
#define INVT 20.0f
#define EPS 1e-6f
// sqrt(20/ln2): gram(Z) = 20*log2(e)*cos, so exp2(gram) = e^{20 cos}
#define ZSCALE 5.3715835f

typedef __attribute__((ext_vector_type(8))) short bf16x8;
typedef __attribute__((ext_vector_type(4))) float f32x4;

#if __has_builtin(__builtin_amdgcn_exp2f)
#define EXP2F(x) __builtin_amdgcn_exp2f(x)
#else
#define EXP2F(x) exp2f(x)
#endif

// Z layout (fragment order): G-row R, element l stored at bf16 index
//   ( (R>>4)*128 + (l>>5)*64 + ((l>>3)&3)*16 + (R&15) )*8 + (l&7)
// so the MFMA fragment load for 16-row group g, K-chunk kc is the fully
// contiguous 1 KB wave load  Zf[g*128 + kc*64 + lane].
//
// HISTORY (keep):
//  - R9/R12: (256,5) spills. (256,4) is the occupancy ceiling.
//  - R10: __threadfence in all blocks -> L2 thrash, 5x slower.
//  - R11 (=R8, 93.1us): 1 tile/block, af+bv resident.
//  - R13 (91.8us): 2 ranks/block, tile1 frags prefetched in tile0 epilogue.
//  - R14/R15 (112/117us REGRESSION): strip-mining with loads at loop top.
//    Counters: VGPR=64 (arch regs only: af+bv; acc/rsum in unified AGPR
//    side), FETCH+WRITE ~131MB == 2.1M col atomics x 64B fabric txns (NOT
//    scratch; R13 had same traffic). Real cause: dynamic t-loop defeated
//    pipelining -> bv load latency exposed + per-iter waits fenced the
//    in-flight atomic; 1024 blocks = exactly-resident -> no balancing.
//  - R16 (this): jj-outer/ii-inner so bv[jj] dies at end of its jj iter;
//    next tile's bv[jj] prefetched in-place there (~1 tile of work ahead).
//    Col atomic issued AFTER all prefetches -> counted vmcnt waits never
//    drain it. 4 tiles/block fully unrolled, 2064 blocks (8256 ranks).

__device__ __forceinline__ void unrank(int t, int& bi, int& bj) {
    int b = (int)((257.0f - sqrtf(66049.0f - 8.0f * (float)t)) * 0.5f);
    while (b * (257 - b) / 2 > t) --b;
    while ((b + 1) * (256 - b) / 2 <= t) ++b;
    bi = b;
    bj = b + (t - b * (257 - b) / 2);
}

// ---------------- Kernel 1: normalize -> scaled bf16 Z (fragment order),
//                  zero part[] / lacc / cnt ----------------
__global__ __launch_bounds__(256) void prep_kernel(
    const float* __restrict__ A, const float* __restrict__ P,
    __hip_bfloat16* __restrict__ Zn, float* __restrict__ diag20,
    float* __restrict__ part, float* __restrict__ lacc, unsigned* __restrict__ cnt) {
    if (blockIdx.x < 64) part[blockIdx.x * 256 + threadIdx.x] = 0.0f;
    else if (blockIdx.x == 64 && threadIdx.x == 0) { *lacc = 0.0f; *cnt = 0u; }

    const int lane = threadIdx.x & 63;   // element index l
    const int w    = threadIdx.x >> 6;
    const int r    = blockIdx.x * 4 + w; // A/P row
    const int u    = lane >> 3, sub = lane & 7;
    const int upos = (u >> 2) * 64 + (u & 3) * 16;   // kc*64 + q*16

    float a = A[r * D + lane];
    float p = P[r * D + lane];
    float sa = a * a, sp = p * p, dp = a * p;
    #pragma unroll
    for (int off = 1; off < 64; off <<= 1) {
        sa += __shfl_xor(sa, off, 64);
        sp += __shfl_xor(sp, off, 64);
        dp += __shfl_xor(dp, off, 64);
    }
    float na  = sqrtf(sa);
    float npn = sqrtf(sp);
    {   // A-row R = r
        int g = r >> 4, l2 = r & 15;
        Zn[(g * 128 + upos + l2) * 8 + sub] = __float2bfloat16(a * (ZSCALE / na));
    }
    {   // P-row R = N + r
        int R = N + r; int g = R >> 4, l2 = R & 15;
        Zn[(g * 128 + upos + l2) * 8 + sub] = __float2bfloat16(p * (ZSCALE / npn));
    }
    if (lane == 0)
        diag20[r] = (dp / fmaxf(na * npn, EPS)) * INVT;
}

// ---------------- Kernel 2: pipelined strip-mined triangular tiles ----------

#define ROW_FLUSH()                                                            \
    {                                                                          \
        *(f32x4*)&rs[w][ln][0 * 16 + q * 4] = rsum0;                           \
        *(f32x4*)&rs[w][ln][1 * 16 + q * 4] = rsum1;                           \
        *(f32x4*)&rs[w][ln][2 * 16 + q * 4] = rsum2;                           \
        *(f32x4*)&rs[w][ln][3 * 16 + q * 4] = rsum3;                           \
        float rowsum = 0.0f;                                                   \
        _Pragma("unroll")                                                      \
        for (int l = 0; l < 16; ++l) rowsum += rs[w][l][lane];                 \
        merged[wc][wr * 64 + lane] = rowsum;                                   \
        __syncthreads();                                                       \
        if (tid < 128)                                                         \
            atomicAdd(part + bi * 128 + tid, merged[0][tid] + merged[1][tid]); \
    }

#define TILE_T(HAVE_NEXT)                                                      \
    {                                                                          \
        const bool dwave = (bi == bj) && (wr == wc);                           \
        const int nbi = (bj == 127) ? (bi + 1) : bi;                           \
        const int nbj = (bj == 127) ? (bi + 1) : (bj + 1);                     \
        float csum0 = 0.0f, csum1 = 0.0f, csum2 = 0.0f, csum3 = 0.0f;          \
        _Pragma("unroll")                                                      \
        for (int jj = 0; jj < 4; ++jj) {                                       \
            f32x4 acc0 = __builtin_amdgcn_mfma_f32_16x16x32_bf16(              \
                af[0][0], bv[jj][0], zero, 0, 0, 0);                           \
            f32x4 acc1 = __builtin_amdgcn_mfma_f32_16x16x32_bf16(              \
                af[1][0], bv[jj][0], zero, 0, 0, 0);                           \
            f32x4 acc2 = __builtin_amdgcn_mfma_f32_16x16x32_bf16(              \
                af[2][0], bv[jj][0], zero, 0, 0, 0);                           \
            f32x4 acc3 = __builtin_amdgcn_mfma_f32_16x16x32_bf16(              \
                af[3][0], bv[jj][0], zero, 0, 0, 0);                           \
            acc0 = __builtin_amdgcn_mfma_f32_16x16x32_bf16(                    \
                af[0][1], bv[jj][1], acc0, 0, 0, 0);                           \
            acc1 = __builtin_amdgcn_mfma_f32_16x16x32_bf16(                    \
                af[1][1], bv[jj][1], acc1, 0, 0, 0);                           \
            acc2 = __builtin_amdgcn_mfma_f32_16x16x32_bf16(                    \
                af[2][1], bv[jj][1], acc2, 0, 0, 0);                           \
            acc3 = __builtin_amdgcn_mfma_f32_16x16x32_bf16(                    \
                af[3][1], bv[jj][1], acc3, 0, 0, 0);                           \
            /* bv[jj] dead: prefetch next tile's fragment in-place. */         \
            if (HAVE_NEXT) {                                                   \
                int gb = nbj * 8 + wc * 4 + jj;                                \
                bv[jj][0] = Zf[gb * 128 + lane];                               \
                bv[jj][1] = Zf[gb * 128 + 64 + lane];                          \
            }                                                                  \
            float cst = 0.0f;                                                  \
            {                                                                  \
                f32x4 e;                                                       \
                _Pragma("unroll")                                              \
                for (int r = 0; r < 4; ++r) e[r] = EXP2F(acc0[r]);             \
                if (dwave && jj == 0) {                                        \
                    _Pragma("unroll")                                          \
                    for (int r = 0; r < 4; ++r)                                \
                        if (ln == q * 4 + r) e[r] = 0.0f;                      \
                }                                                              \
                rsum0 += e; cst += (e[0] + e[1]) + (e[2] + e[3]);              \
            }                                                                  \
            {                                                                  \
                f32x4 e;                                                       \
                _Pragma("unroll")                                              \
                for (int r = 0; r < 4; ++r) e[r] = EXP2F(acc1[r]);             \
                if (dwave && jj == 1) {                                        \
                    _Pragma("unroll")                                          \
                    for (int r = 0; r < 4; ++r)                                \
                        if (ln == q * 4 + r) e[r] = 0.0f;                      \
                }                                                              \
                rsum1 += e; cst += (e[0] + e[1]) + (e[2] + e[3]);              \
            }                                                                  \
            {                                                                  \
                f32x4 e;                                                       \
                _Pragma("unroll")                                              \
                for (int r = 0; r < 4; ++r) e[r] = EXP2F(acc2[r]);             \
                if (dwave && jj == 2) {                                        \
                    _Pragma("unroll")                                          \
                    for (int r = 0; r < 4; ++r)                                \
                        if (ln == q * 4 + r) e[r] = 0.0f;                      \
                }                                                              \
                rsum2 += e; cst += (e[0] + e[1]) + (e[2] + e[3]);              \
            }                                                                  \
            {                                                                  \
                f32x4 e;                                                       \
                _Pragma("unroll")                                              \
                for (int r = 0; r < 4; ++r) e[r] = EXP2F(acc3[r]);             \
                if (dwave && jj == 3) {                                        \
                    _Pragma("unroll")                                          \
                    for (int r = 0; r < 4; ++r)                                \
                        if (ln == q * 4 + r) e[r] = 0.0f;                      \
                }                                                              \
                rsum3 += e; cst += (e[0] + e[1]) + (e[2] + e[3]);              \
            }                                                                  \
            if (jj == 0) csum0 = cst;                                          \
            else if (jj == 1) csum1 = cst;                                     \
            else if (jj == 2) csum2 = cst;                                     \
            else csum3 = cst;                                                  \
        }                                                                      \
        /* col flush: issued AFTER all prefetch loads -> stays in flight */    \
        if (bi != bj) {                                                        \
            csum0 += __shfl_xor(csum0, 16, 64);                                \
            csum0 += __shfl_xor(csum0, 32, 64);                                \
            csum1 += __shfl_xor(csum1, 16, 64);                                \
            csum1 += __shfl_xor(csum1, 32, 64);                                \
            csum2 += __shfl_xor(csum2, 16, 64);                                \
            csum2 += __shfl_xor(csum2, 32, 64);                                \
            csum3 += __shfl_xor(csum3, 16, 64);                                \
            csum3 += __shfl_xor(csum3, 32, 64);                                \
            float cval = (q == 0) ? csum0 : (q == 1) ? csum1                   \
                       : (q == 2) ? csum2 : csum3;                             \
            atomicAdd(part + bj * 128 + wc * 64 + lane, cval);                 \
        }                                                                      \
        if (HAVE_NEXT) {                                                       \
            if (bj == 127) {                                                   \
                ROW_FLUSH();                                                   \
                __syncthreads();                                               \
                rsum0 = zero; rsum1 = zero; rsum2 = zero; rsum3 = zero;        \
                bi = nbi; bj = nbj;                                            \
                _Pragma("unroll")                                              \
                for (int ii = 0; ii < 4; ++ii) {                               \
                    int ga = bi * 8 + wr * 4 + ii;                             \
                    af[ii][0] = Zf[ga * 128 + lane];                           \
                    af[ii][1] = Zf[ga * 128 + 64 + lane];                      \
                }                                                              \
            } else {                                                           \
                bi = nbi; bj = nbj;                                            \
            }                                                                  \
        }                                                                      \
    }

__global__ __launch_bounds__(256, 4) void tiles_kernel(
    const __hip_bfloat16* __restrict__ Zn, float* __restrict__ part) {
    __shared__ float rs[4][16][68];     // wave-local transpose; 2-way banks max
    __shared__ float merged[2][128];    // row merge over wc (flush only)

    const int tid = threadIdx.x;
    const int lane = tid & 63, w = tid >> 6;
    const int wr = w >> 1, wc = w & 1;
    const int ln = lane & 15, q = lane >> 4;
    const bf16x8* Zf = (const bf16x8*)Zn;
    const f32x4 zero = {0.0f, 0.0f, 0.0f, 0.0f};

    int bi, bj;
    unrank((int)blockIdx.x * 4, bi, bj);

    // A fragments, register-resident per row segment
    bf16x8 af[4][2];
    #pragma unroll
    for (int ii = 0; ii < 4; ++ii) {
        int ga = bi * 8 + wr * 4 + ii;
        af[ii][0] = Zf[ga * 128 + lane];
        af[ii][1] = Zf[ga * 128 + 64 + lane];
    }
    // B fragments for tile 0
    bf16x8 bv[4][2];
    #pragma unroll
    for (int jj = 0; jj < 4; ++jj) {
        int gb = bj * 8 + wc * 4 + jj;
        bv[jj][0] = Zf[gb * 128 + lane];
        bv[jj][1] = Zf[gb * 128 + 64 + lane];
    }

    f32x4 rsum0 = zero, rsum1 = zero, rsum2 = zero, rsum3 = zero;

    TILE_T(true)
    TILE_T(true)
    TILE_T(true)
    TILE_T(false)

    ROW_FLUSH();
}

// ---------------- Kernel 3: per-row loss + reduce + last-block finalize ------
__global__ __launch_bounds__(256) void loss_kernel(
    const float* __restrict__ part, const float* __restrict__ diag20,
    float* __restrict__ lacc, unsigned* __restrict__ cnt, float* __restrict__ out) {
    int i = blockIdx.x * 256 + threadIdx.x;
    float v = logf(part[i] + part[N + i]) - diag20[i];
    #pragma unroll
    for (int off = 32; off > 0; off >>= 1) v += __shfl_down(v, off, 64);
    __shared__ float wsm[4];
    int lane = threadIdx.x & 63, wv = threadIdx.x >> 6;
    if (lane == 0) wsm[wv] = v;
    __syncthreads();
    if (threadIdx.x == 0) {
        atomicAdd(lacc, wsm[0] + wsm[1] + wsm[2] + wsm[3]);
        __threadfence();
        unsigned old = atomicAdd(cnt, 1u);
        if (old == (N / 256 - 1)) {
            float tot = atomicAdd(lacc, 0.0f);
            out[0] = tot * (1.0f / (float)N);
        }
    }
}

// ---------------- launch ----------------
extern "C" void kernel_launch(void* const* d_in, const int* in_sizes, int n_in,
                              void* d_out, int out_size, void* d_ws, size_t ws_size,
                              hipStream_t stream) {
    const float* A = (const float*)d_in[0];
    const float* P = (const float*)d_in[1];

    __hip_bfloat16* Zn = (__hip_bfloat16*)d_ws;                 // 2N*64 bf16 = 2 MiB
    float* diag20 = (float*)((char*)d_ws + 2u * N * D * sizeof(__hip_bfloat16));
    float* part   = diag20 + N;          // 2N floats, atomic-accumulated
    float* lacc   = part + 2 * N;
    unsigned* cnt = (unsigned*)(lacc + 1);

    prep_kernel<<<N / 4, 256, 0, stream>>>(A, P, Zn, diag20, part, lacc, cnt);

    tiles_kernel<<<2064, 256, 0, stream>>>(Zn, part);  // 8256 ranks, 4/block

    loss_kernel<<<N / 256, 256, 0, stream>>>(part, diag20, lacc, cnt, (float*)d_out);
}

// Round 4
// 107.472 us; speedup vs baseline: 1.3976x; 1.3976x over previous
//
#include <hip/hip_runtime.h>
#include <hip/hip_bf16.h>
#include <math.h>

#define N 8192
#define D 64
#define INVT 20.0f
#define EPS 1e-6f
// sqrt(20/ln2): gram(Z) = 20*log2(e)*cos, so exp2(gram) = e^{20 cos}
#define ZSCALE 5.3715835f
#define NTILES 8256   // 128*129/2 triangular ranks

typedef __attribute__((ext_vector_type(8))) short bf16x8;
typedef __attribute__((ext_vector_type(4))) float f32x4;

#if __has_builtin(__builtin_amdgcn_exp2f)
#define EXP2F(x) __builtin_amdgcn_exp2f(x)
#else
#define EXP2F(x) exp2f(x)
#endif

// Z layout (fragment order): G-row R, element l stored at bf16 index
//   ( (R>>4)*128 + (l>>5)*64 + ((l>>3)&3)*16 + (R&15) )*8 + (l&7)
// so the MFMA fragment load for 16-row group g, K-chunk kc is the fully
// contiguous 1 KB wave load  Zf[g*128 + kc*64 + lane].
//
// HISTORY (keep):
//  - R9/R12: (256,5) spills. (256,4) is the occupancy ceiling.
//  - R10: __threadfence in all blocks -> L2 thrash, 5x slower.
//  - R11 (=R8, 93.1us): 1 tile/block, af+bv resident, (256,4).
//  - R13 (91.8us, BEST): 2 ranks/block, tile1 frags prefetched during tile0
//    epilogue. Straight-line, compiler-friendly. THIS is the base.
//  - R14/R15 (112/117us): strip-mining, loads at loop top. Dynamic loop
//    defeated pipelining; FETCH+WRITE ~131MB == 2.1M part[] atomics x 64B
//    line ping-pong across 8 non-coherent XCD L2s (constant tax since R8).
//  - R16 (150us): 4-tile full unroll -> register overrun, scratch spill
//    (WRITE 219MB). Strip-mining axis ABANDONED: it fights the compiler.
//  - R17 (this): R13 verbatim, but NO device atomics in tiles_kernel: each
//    tile stores its 128 row-sums / 128 col-sums to rowbuf/colbuf[t][128]
//    (plain coalesced stores, 8.4MB). New reduce_kernel gathers per-part-row
//    (row ranks contiguous: base=bi*(257-bi)/2; col ranks closed-form),
//    exactly 128 coalesced reads/thread. Kills the 131MB coherence thrash.

__device__ __forceinline__ void unrank(int t, int& bi, int& bj) {
    int b = (int)((257.0f - sqrtf(66049.0f - 8.0f * (float)t)) * 0.5f);
    while (b * (257 - b) / 2 > t) --b;
    while ((b + 1) * (256 - b) / 2 <= t) ++b;
    bi = b;
    bj = b + (t - b * (257 - b) / 2);
}

// ---------------- Kernel 1: normalize -> scaled bf16 Z (fragment order) -----
__global__ __launch_bounds__(256) void prep_kernel(
    const float* __restrict__ A, const float* __restrict__ P,
    __hip_bfloat16* __restrict__ Zn, float* __restrict__ diag20,
    float* __restrict__ lacc, unsigned* __restrict__ cnt) {
    if (blockIdx.x == 0 && threadIdx.x == 0) { *lacc = 0.0f; *cnt = 0u; }

    const int lane = threadIdx.x & 63;   // element index l
    const int w    = threadIdx.x >> 6;
    const int r    = blockIdx.x * 4 + w; // A/P row
    const int u    = lane >> 3, sub = lane & 7;
    const int upos = (u >> 2) * 64 + (u & 3) * 16;   // kc*64 + q*16

    float a = A[r * D + lane];
    float p = P[r * D + lane];
    float sa = a * a, sp = p * p, dp = a * p;
    #pragma unroll
    for (int off = 1; off < 64; off <<= 1) {
        sa += __shfl_xor(sa, off, 64);
        sp += __shfl_xor(sp, off, 64);
        dp += __shfl_xor(dp, off, 64);
    }
    float na  = sqrtf(sa);
    float npn = sqrtf(sp);
    {   // A-row R = r
        int g = r >> 4, l2 = r & 15;
        Zn[(g * 128 + upos + l2) * 8 + sub] = __float2bfloat16(a * (ZSCALE / na));
    }
    {   // P-row R = N + r
        int R = N + r; int g = R >> 4, l2 = R & 15;
        Zn[(g * 128 + upos + l2) * 8 + sub] = __float2bfloat16(p * (ZSCALE / npn));
    }
    if (lane == 0)
        diag20[r] = (dp / fmaxf(na * npn, EPS)) * INVT;
}

// ---------------- Kernel 2: two triangular ranks per block, prefetched ------
// (R13 structure verbatim; atomics replaced by per-tile rowbuf/colbuf stores)
__global__ __launch_bounds__(256, 4) void tiles_kernel(
    const __hip_bfloat16* __restrict__ Zn,
    float* __restrict__ rowbuf, float* __restrict__ colbuf) {
    __shared__ float rs[4][16][68];     // wave-local transpose; 2-way banks max
    __shared__ float merged[2][128];    // row merge over wc
    __shared__ float cmerged[2][2][64]; // col merge over wr: [wr][wc][col]

    const int tid = threadIdx.x;
    const int lane = tid & 63, w = tid >> 6;
    const int wr = w >> 1, wc = w & 1;
    const int ln = lane & 15, q = lane >> 4;
    const bf16x8* Zf = (const bf16x8*)Zn;

    const int t0 = 2 * (int)blockIdx.x;
    const int t1 = t0 + 1;
    int bi0, bj0, bi1, bj1;
    unrank(t0, bi0, bj0);
    unrank(t1, bi1, bj1);

    const f32x4 zero = {0.0f, 0.0f, 0.0f, 0.0f};

    // ---------------- tile 0: load fragments ----------------
    bf16x8 af0[4][2], bv0[4][2];
    #pragma unroll
    for (int ii = 0; ii < 4; ++ii) {
        int ga = bi0 * 8 + wr * 4 + ii;
        int gb = bj0 * 8 + wc * 4 + ii;
        #pragma unroll
        for (int kc = 0; kc < 2; ++kc) {
            af0[ii][kc] = Zf[ga * 128 + kc * 64 + lane];
            bv0[ii][kc] = Zf[gb * 128 + kc * 64 + lane];
        }
    }

    // ---------------- tile 0: stripes (MFMA + exp) ----------------
    const bool dwave0 = (bi0 == bj0) && (wr == wc);
    float csum[4] = {0.0f, 0.0f, 0.0f, 0.0f};
    #pragma unroll
    for (int ii = 0; ii < 4; ++ii) {
        f32x4 acc[4];
        #pragma unroll
        for (int jj = 0; jj < 4; ++jj)
            acc[jj] = __builtin_amdgcn_mfma_f32_16x16x32_bf16(
                af0[ii][0], bv0[jj][0], zero, 0, 0, 0);
        #pragma unroll
        for (int jj = 0; jj < 4; ++jj)
            acc[jj] = __builtin_amdgcn_mfma_f32_16x16x32_bf16(
                af0[ii][1], bv0[jj][1], acc[jj], 0, 0, 0);

        f32x4 rsum_ii = {};
        #pragma unroll
        for (int jj = 0; jj < 4; ++jj) {
            f32x4 e;
            #pragma unroll
            for (int r = 0; r < 4; ++r) e[r] = EXP2F(acc[jj][r]);
            if (dwave0 && (ii == jj)) {
                #pragma unroll
                for (int r = 0; r < 4; ++r)
                    if (ln == q * 4 + r) e[r] = 0.0f;
            }
            rsum_ii += e;
            csum[jj] += (e[0] + e[1]) + (e[2] + e[3]);
        }
        *(f32x4*)&rs[w][ln][ii * 16 + q * 4] = rsum_ii;
    }

    // ---------------- prefetch tile 1 fragments ----------------
    bf16x8 af1[4][2], bv1[4][2];
    #pragma unroll
    for (int ii = 0; ii < 4; ++ii) {
        int ga = bi1 * 8 + wr * 4 + ii;
        int gb = bj1 * 8 + wc * 4 + ii;
        #pragma unroll
        for (int kc = 0; kc < 2; ++kc) {
            af1[ii][kc] = Zf[ga * 128 + kc * 64 + lane];
            bv1[ii][kc] = Zf[gb * 128 + kc * 64 + lane];
        }
    }

    // ---------------- tile 0: reductions + stores ----------------
    {
        float rowsum = 0.0f;
        #pragma unroll
        for (int l = 0; l < 16; ++l) rowsum += rs[w][l][lane];
        merged[wc][wr * 64 + lane] = rowsum;

        float cs0 = csum[0], cs1 = csum[1], cs2 = csum[2], cs3 = csum[3];
        cs0 += __shfl_xor(cs0, 16, 64); cs0 += __shfl_xor(cs0, 32, 64);
        cs1 += __shfl_xor(cs1, 16, 64); cs1 += __shfl_xor(cs1, 32, 64);
        cs2 += __shfl_xor(cs2, 16, 64); cs2 += __shfl_xor(cs2, 32, 64);
        cs3 += __shfl_xor(cs3, 16, 64); cs3 += __shfl_xor(cs3, 32, 64);
        float cval = (q == 0) ? cs0 : (q == 1) ? cs1 : (q == 2) ? cs2 : cs3;
        cmerged[wr][wc][q * 16 + ln] = cval;
        __syncthreads();

        if (tid < 128) {
            rowbuf[t0 * 128 + tid] = merged[0][tid] + merged[1][tid];
        } else if (bi0 != bj0) {
            int col = tid - 128;
            colbuf[t0 * 128 + col] =
                cmerged[0][col >> 6][col & 63] + cmerged[1][col >> 6][col & 63];
        }
    }
    __syncthreads();   // protect merged/cmerged before tile1 rewrites them

    // ---------------- tile 1: stripes (MFMA + exp) ----------------
    const bool dwave1 = (bi1 == bj1) && (wr == wc);
    float csumB[4] = {0.0f, 0.0f, 0.0f, 0.0f};
    #pragma unroll
    for (int ii = 0; ii < 4; ++ii) {
        f32x4 acc[4];
        #pragma unroll
        for (int jj = 0; jj < 4; ++jj)
            acc[jj] = __builtin_amdgcn_mfma_f32_16x16x32_bf16(
                af1[ii][0], bv1[jj][0], zero, 0, 0, 0);
        #pragma unroll
        for (int jj = 0; jj < 4; ++jj)
            acc[jj] = __builtin_amdgcn_mfma_f32_16x16x32_bf16(
                af1[ii][1], bv1[jj][1], acc[jj], 0, 0, 0);

        f32x4 rsum_ii = {};
        #pragma unroll
        for (int jj = 0; jj < 4; ++jj) {
            f32x4 e;
            #pragma unroll
            for (int r = 0; r < 4; ++r) e[r] = EXP2F(acc[jj][r]);
            if (dwave1 && (ii == jj)) {
                #pragma unroll
                for (int r = 0; r < 4; ++r)
                    if (ln == q * 4 + r) e[r] = 0.0f;
            }
            rsum_ii += e;
            csumB[jj] += (e[0] + e[1]) + (e[2] + e[3]);
        }
        *(f32x4*)&rs[w][ln][ii * 16 + q * 4] = rsum_ii;
    }

    // ---------------- tile 1: reductions + stores ----------------
    {
        float rowsum = 0.0f;
        #pragma unroll
        for (int l = 0; l < 16; ++l) rowsum += rs[w][l][lane];
        merged[wc][wr * 64 + lane] = rowsum;

        float cs0 = csumB[0], cs1 = csumB[1], cs2 = csumB[2], cs3 = csumB[3];
        cs0 += __shfl_xor(cs0, 16, 64); cs0 += __shfl_xor(cs0, 32, 64);
        cs1 += __shfl_xor(cs1, 16, 64); cs1 += __shfl_xor(cs1, 32, 64);
        cs2 += __shfl_xor(cs2, 16, 64); cs2 += __shfl_xor(cs2, 32, 64);
        cs3 += __shfl_xor(cs3, 16, 64); cs3 += __shfl_xor(cs3, 32, 64);
        float cval = (q == 0) ? cs0 : (q == 1) ? cs1 : (q == 2) ? cs2 : cs3;
        cmerged[wr][wc][q * 16 + ln] = cval;
        __syncthreads();

        if (tid < 128) {
            rowbuf[t1 * 128 + tid] = merged[0][tid] + merged[1][tid];
        } else if (bi1 != bj1) {
            int col = tid - 128;
            colbuf[t1 * 128 + col] =
                cmerged[0][col >> 6][col & 63] + cmerged[1][col >> 6][col & 63];
        }
    }
}

// ---------------- Kernel 2.5: gather per-tile partials -> part[] ------------
// part[R], R = bi*128 + c. Row side: ranks [bi*(257-bi)/2, +128-bi) are the
// tiles (bi, bi..127) -- contiguous. Col side: rank(r,bi) = r*(257-r)/2+(bi-r)
// for r < bi (diag ranks excluded naturally). Exactly 128 reads per thread;
// 128 consecutive threads share bi -> every read is a contiguous 512B line.
__global__ __launch_bounds__(256) void reduce_kernel(
    const float* __restrict__ rowbuf, const float* __restrict__ colbuf,
    float* __restrict__ part) {
    const int R  = (int)blockIdx.x * 256 + (int)threadIdx.x;
    const int bi = R >> 7, c = R & 127;
    const int base = bi * (257 - bi) / 2;

    float s = 0.0f;
    const int nrow = 128 - bi;
    #pragma unroll 4
    for (int k = 0; k < nrow; ++k)
        s += rowbuf[(base + k) * 128 + c];
    #pragma unroll 4
    for (int r = 0; r < bi; ++r)
        s += colbuf[(r * (257 - r) / 2 + (bi - r)) * 128 + c];
    part[R] = s;
}

// ---------------- Kernel 3: per-row loss + reduce + last-block finalize ------
__global__ __launch_bounds__(256) void loss_kernel(
    const float* __restrict__ part, const float* __restrict__ diag20,
    float* __restrict__ lacc, unsigned* __restrict__ cnt, float* __restrict__ out) {
    int i = blockIdx.x * 256 + threadIdx.x;
    float v = logf(part[i] + part[N + i]) - diag20[i];
    #pragma unroll
    for (int off = 32; off > 0; off >>= 1) v += __shfl_down(v, off, 64);
    __shared__ float wsm[4];
    int lane = threadIdx.x & 63, wv = threadIdx.x >> 6;
    if (lane == 0) wsm[wv] = v;
    __syncthreads();
    if (threadIdx.x == 0) {
        atomicAdd(lacc, wsm[0] + wsm[1] + wsm[2] + wsm[3]);
        __threadfence();
        unsigned old = atomicAdd(cnt, 1u);
        if (old == (N / 256 - 1)) {
            float tot = atomicAdd(lacc, 0.0f);
            out[0] = tot * (1.0f / (float)N);
        }
    }
}

// ---------------- launch ----------------
extern "C" void kernel_launch(void* const* d_in, const int* in_sizes, int n_in,
                              void* d_out, int out_size, void* d_ws, size_t ws_size,
                              hipStream_t stream) {
    const float* A = (const float*)d_in[0];
    const float* P = (const float*)d_in[1];

    __hip_bfloat16* Zn = (__hip_bfloat16*)d_ws;                 // 2N*64 bf16 = 2 MiB
    float* diag20 = (float*)((char*)d_ws + 2u * N * D * sizeof(__hip_bfloat16));
    float* rowbuf = diag20 + N;                 // NTILES*128 floats = 4.2 MB
    float* colbuf = rowbuf + NTILES * 128;      // NTILES*128 floats = 4.2 MB
    float* part   = colbuf + NTILES * 128;      // 2N floats
    float* lacc   = part + 2 * N;
    unsigned* cnt = (unsigned*)(lacc + 1);

    prep_kernel<<<N / 4, 256, 0, stream>>>(A, P, Zn, diag20, lacc, cnt);

    tiles_kernel<<<NTILES / 2, 256, 0, stream>>>(Zn, rowbuf, colbuf);

    reduce_kernel<<<2 * N / 256, 256, 0, stream>>>(rowbuf, colbuf, part);

    loss_kernel<<<N / 256, 256, 0, stream>>>(part, diag20, lacc, cnt, (float*)d_out);
}

// Round 5
// 101.110 us; speedup vs baseline: 1.4856x; 1.0629x over previous
//
#include <hip/hip_runtime.h>
#include <hip/hip_bf16.h>
#include <math.h>

#define N 8192
#define D 64
#define INVT 20.0f
#define EPS 1e-6f
// sqrt(20/ln2): gram(Z) = 20*log2(e)*cos, so exp2(gram) = e^{20 cos}
#define ZSCALE 5.3715835f
#define NTILES 8256   // 128*129/2 triangular ranks

typedef __attribute__((ext_vector_type(8))) short bf16x8;
typedef __attribute__((ext_vector_type(4))) float f32x4;

#if __has_builtin(__builtin_amdgcn_exp2f)
#define EXP2F(x) __builtin_amdgcn_exp2f(x)
#else
#define EXP2F(x) exp2f(x)
#endif

// Z layout (fragment order): G-row R, element l stored at bf16 index
//   ( (R>>4)*128 + (l>>5)*64 + ((l>>3)&3)*16 + (R&15) )*8 + (l&7)
// MFMA fragment load for 16-row group g, K-chunk kc = contiguous 1 KB wave
// load Zf[g*128 + kc*64 + lane].
//
// HISTORY (keep):
//  - R9/R12: (256,5) spills. (256,4) is the occupancy ceiling.
//  - R10: __threadfence in all blocks -> L2 thrash, 5x slower.
//  - R11 (93.1us): 1 tile/block. R13 (91.8us): 2 ranks/block + prefetch ->
//    only 1.4% better => fragment-load latency is NOT the main stall.
//  - R14/R15 (112/117us): strip-mining defeated pipelining. R16 (150us):
//    4-tile unroll -> spill. Restructure axis ABANDONED.
//  - R17 (107.5us): atomics -> rowbuf/colbuf + reduce_kernel. Tiles fell
//    below the 42us fills, but reduce_kernel was 64 blocks x 128
//    cross-XCD-miss loads/thread = latency-bound ~12-15us. Net regression.
//  - R18 (this): (a) reduce_kernel 256 blocks, 4 threads/output x 32 loads,
//    LDS combine -> ~2-3us. (b) tile0 stores overlap tile1 stripes (barrier
//    moved after stripes; stripes touch only per-wave rs[w] -> race-free).
//    (c) af1 reload skipped when bi1==bi0 (4064/4128 pairs) -> -25% L2.

__device__ __forceinline__ void unrank(int t, int& bi, int& bj) {
    int b = (int)((257.0f - sqrtf(66049.0f - 8.0f * (float)t)) * 0.5f);
    while (b * (257 - b) / 2 > t) --b;
    while ((b + 1) * (256 - b) / 2 <= t) ++b;
    bi = b;
    bj = b + (t - b * (257 - b) / 2);
}

// ---------------- Kernel 1: normalize -> scaled bf16 Z (fragment order) -----
__global__ __launch_bounds__(256) void prep_kernel(
    const float* __restrict__ A, const float* __restrict__ P,
    __hip_bfloat16* __restrict__ Zn, float* __restrict__ diag20,
    float* __restrict__ lacc, unsigned* __restrict__ cnt) {
    if (blockIdx.x == 0 && threadIdx.x == 0) { *lacc = 0.0f; *cnt = 0u; }

    const int lane = threadIdx.x & 63;   // element index l
    const int w    = threadIdx.x >> 6;
    const int r    = blockIdx.x * 4 + w; // A/P row
    const int u    = lane >> 3, sub = lane & 7;
    const int upos = (u >> 2) * 64 + (u & 3) * 16;   // kc*64 + q*16

    float a = A[r * D + lane];
    float p = P[r * D + lane];
    float sa = a * a, sp = p * p, dp = a * p;
    #pragma unroll
    for (int off = 1; off < 64; off <<= 1) {
        sa += __shfl_xor(sa, off, 64);
        sp += __shfl_xor(sp, off, 64);
        dp += __shfl_xor(dp, off, 64);
    }
    float na  = sqrtf(sa);
    float npn = sqrtf(sp);
    {   // A-row R = r
        int g = r >> 4, l2 = r & 15;
        Zn[(g * 128 + upos + l2) * 8 + sub] = __float2bfloat16(a * (ZSCALE / na));
    }
    {   // P-row R = N + r
        int R = N + r; int g = R >> 4, l2 = R & 15;
        Zn[(g * 128 + upos + l2) * 8 + sub] = __float2bfloat16(p * (ZSCALE / npn));
    }
    if (lane == 0)
        diag20[r] = (dp / fmaxf(na * npn, EPS)) * INVT;
}

// ---------------- Kernel 2: two triangular ranks per block ------------------
__global__ __launch_bounds__(256, 4) void tiles_kernel(
    const __hip_bfloat16* __restrict__ Zn,
    float* __restrict__ rowbuf, float* __restrict__ colbuf) {
    __shared__ float rs[4][16][68];     // wave-local transpose; 2-way banks max
    __shared__ float merged[2][128];    // row merge over wc
    __shared__ float cmerged[2][2][64]; // col merge over wr: [wr][wc][col]

    const int tid = threadIdx.x;
    const int lane = tid & 63, w = tid >> 6;
    const int wr = w >> 1, wc = w & 1;
    const int ln = lane & 15, q = lane >> 4;
    const bf16x8* Zf = (const bf16x8*)Zn;

    const int t0 = 2 * (int)blockIdx.x;
    const int t1 = t0 + 1;
    int bi0, bj0, bi1, bj1;
    unrank(t0, bi0, bj0);
    unrank(t1, bi1, bj1);

    const f32x4 zero = {0.0f, 0.0f, 0.0f, 0.0f};

    // ---------------- tile 0: load fragments ----------------
    bf16x8 af0[4][2], bv0[4][2];
    #pragma unroll
    for (int ii = 0; ii < 4; ++ii) {
        int ga = bi0 * 8 + wr * 4 + ii;
        int gb = bj0 * 8 + wc * 4 + ii;
        #pragma unroll
        for (int kc = 0; kc < 2; ++kc) {
            af0[ii][kc] = Zf[ga * 128 + kc * 64 + lane];
            bv0[ii][kc] = Zf[gb * 128 + kc * 64 + lane];
        }
    }

    // ---------------- tile 0: stripes (MFMA + exp) ----------------
    const bool dwave0 = (bi0 == bj0) && (wr == wc);
    float csum[4] = {0.0f, 0.0f, 0.0f, 0.0f};
    #pragma unroll
    for (int ii = 0; ii < 4; ++ii) {
        f32x4 acc[4];
        #pragma unroll
        for (int jj = 0; jj < 4; ++jj)
            acc[jj] = __builtin_amdgcn_mfma_f32_16x16x32_bf16(
                af0[ii][0], bv0[jj][0], zero, 0, 0, 0);
        #pragma unroll
        for (int jj = 0; jj < 4; ++jj)
            acc[jj] = __builtin_amdgcn_mfma_f32_16x16x32_bf16(
                af0[ii][1], bv0[jj][1], acc[jj], 0, 0, 0);

        f32x4 rsum_ii = {};
        #pragma unroll
        for (int jj = 0; jj < 4; ++jj) {
            f32x4 e;
            #pragma unroll
            for (int r = 0; r < 4; ++r) e[r] = EXP2F(acc[jj][r]);
            if (dwave0 && (ii == jj)) {
                #pragma unroll
                for (int r = 0; r < 4; ++r)
                    if (ln == q * 4 + r) e[r] = 0.0f;
            }
            rsum_ii += e;
            csum[jj] += (e[0] + e[1]) + (e[2] + e[3]);
        }
        *(f32x4*)&rs[w][ln][ii * 16 + q * 4] = rsum_ii;
    }

    // ---------------- prefetch tile 1 fragments ----------------
    // af reused when the pair stays in the same row block (4064/4128 pairs).
    bf16x8 af1[4][2], bv1[4][2];
    #pragma unroll
    for (int ii = 0; ii < 4; ++ii) {
        int gb = bj1 * 8 + wc * 4 + ii;
        #pragma unroll
        for (int kc = 0; kc < 2; ++kc)
            bv1[ii][kc] = Zf[gb * 128 + kc * 64 + lane];
    }
    if (bi1 == bi0) {
        #pragma unroll
        for (int ii = 0; ii < 4; ++ii) {
            af1[ii][0] = af0[ii][0];
            af1[ii][1] = af0[ii][1];
        }
    } else {
        #pragma unroll
        for (int ii = 0; ii < 4; ++ii) {
            int ga = bi1 * 8 + wr * 4 + ii;
            #pragma unroll
            for (int kc = 0; kc < 2; ++kc)
                af1[ii][kc] = Zf[ga * 128 + kc * 64 + lane];
        }
    }

    // ---------------- tile 0: reductions + stores ----------------
    {
        float rowsum = 0.0f;
        #pragma unroll
        for (int l = 0; l < 16; ++l) rowsum += rs[w][l][lane];
        merged[wc][wr * 64 + lane] = rowsum;

        float cs0 = csum[0], cs1 = csum[1], cs2 = csum[2], cs3 = csum[3];
        cs0 += __shfl_xor(cs0, 16, 64); cs0 += __shfl_xor(cs0, 32, 64);
        cs1 += __shfl_xor(cs1, 16, 64); cs1 += __shfl_xor(cs1, 32, 64);
        cs2 += __shfl_xor(cs2, 16, 64); cs2 += __shfl_xor(cs2, 32, 64);
        cs3 += __shfl_xor(cs3, 16, 64); cs3 += __shfl_xor(cs3, 32, 64);
        float cval = (q == 0) ? cs0 : (q == 1) ? cs1 : (q == 2) ? cs2 : cs3;
        cmerged[wr][wc][q * 16 + ln] = cval;
        __syncthreads();

        if (tid < 128) {
            rowbuf[t0 * 128 + tid] = merged[0][tid] + merged[1][tid];
        } else if (bi0 != bj0) {
            int col = tid - 128;
            colbuf[t0 * 128 + col] =
                cmerged[0][col >> 6][col & 63] + cmerged[1][col >> 6][col & 63];
        }
    }
    // NOTE: no barrier here (R18). Tile-1 stripes only write per-wave rs[w],
    // so tile-0's merged/cmerged stores overlap the next MFMA/exp phase.

    // ---------------- tile 1: stripes (MFMA + exp) ----------------
    const bool dwave1 = (bi1 == bj1) && (wr == wc);
    float csumB[4] = {0.0f, 0.0f, 0.0f, 0.0f};
    #pragma unroll
    for (int ii = 0; ii < 4; ++ii) {
        f32x4 acc[4];
        #pragma unroll
        for (int jj = 0; jj < 4; ++jj)
            acc[jj] = __builtin_amdgcn_mfma_f32_16x16x32_bf16(
                af1[ii][0], bv1[jj][0], zero, 0, 0, 0);
        #pragma unroll
        for (int jj = 0; jj < 4; ++jj)
            acc[jj] = __builtin_amdgcn_mfma_f32_16x16x32_bf16(
                af1[ii][1], bv1[jj][1], acc[jj], 0, 0, 0);

        f32x4 rsum_ii = {};
        #pragma unroll
        for (int jj = 0; jj < 4; ++jj) {
            f32x4 e;
            #pragma unroll
            for (int r = 0; r < 4; ++r) e[r] = EXP2F(acc[jj][r]);
            if (dwave1 && (ii == jj)) {
                #pragma unroll
                for (int r = 0; r < 4; ++r)
                    if (ln == q * 4 + r) e[r] = 0.0f;
            }
            rsum_ii += e;
            csumB[jj] += (e[0] + e[1]) + (e[2] + e[3]);
        }
        *(f32x4*)&rs[w][ln][ii * 16 + q * 4] = rsum_ii;
    }

    __syncthreads();   // moved barrier: tile0 merged/cmerged reads are done

    // ---------------- tile 1: reductions + stores ----------------
    {
        float rowsum = 0.0f;
        #pragma unroll
        for (int l = 0; l < 16; ++l) rowsum += rs[w][l][lane];
        merged[wc][wr * 64 + lane] = rowsum;

        float cs0 = csumB[0], cs1 = csumB[1], cs2 = csumB[2], cs3 = csumB[3];
        cs0 += __shfl_xor(cs0, 16, 64); cs0 += __shfl_xor(cs0, 32, 64);
        cs1 += __shfl_xor(cs1, 16, 64); cs1 += __shfl_xor(cs1, 32, 64);
        cs2 += __shfl_xor(cs2, 16, 64); cs2 += __shfl_xor(cs2, 32, 64);
        cs3 += __shfl_xor(cs3, 16, 64); cs3 += __shfl_xor(cs3, 32, 64);
        float cval = (q == 0) ? cs0 : (q == 1) ? cs1 : (q == 2) ? cs2 : cs3;
        cmerged[wr][wc][q * 16 + ln] = cval;
        __syncthreads();

        if (tid < 128) {
            rowbuf[t1 * 128 + tid] = merged[0][tid] + merged[1][tid];
        } else if (bi1 != bj1) {
            int col = tid - 128;
            colbuf[t1 * 128 + col] =
                cmerged[0][col >> 6][col & 63] + cmerged[1][col >> 6][col & 63];
        }
    }
}

// ---------------- Kernel 2.5: gather per-tile partials -> part[] ------------
// part[R], R = bi*128 + c, needs 128 summands: rowbuf ranks
// [base, base+128-bi) (tiles (bi, bi..127), contiguous) then colbuf ranks
// rank(r,bi) = r*(257-r)/2 + (bi-r), r < bi. colbuf == rowbuf + NTILES*128,
// so col summand t-index = NTILES + rank. 256 blocks: block b -> bi = b>>1,
// cols (b&1)*64..+64. 4 threads per output (h = tid>>6, wave-uniform), 32
// loads each (unroll 8 -> deep in flight), LDS combine. Fixes R17's 64-block
// latency-bound gather.
__global__ __launch_bounds__(256) void reduce_kernel(
    const float* __restrict__ rowbuf, float* __restrict__ part) {
    __shared__ float red[4][64];
    const int b    = (int)blockIdx.x;
    const int bi   = b >> 1;
    const int cb   = (b & 1) * 64;
    const int ci   = (int)threadIdx.x & 63;
    const int h    = (int)threadIdx.x >> 6;   // 0..3, wave-uniform
    const int c    = cb + ci;
    const int nrow = 128 - bi;
    const int base = bi * (257 - bi) / 2;

    float s = 0.0f;
    #pragma unroll 8
    for (int k = h * 32; k < h * 32 + 32; ++k) {
        int t;
        if (k < nrow) {
            t = base + k;
        } else {
            int r = k - nrow;
            t = NTILES + r * (257 - r) / 2 + (bi - r);
        }
        s += rowbuf[t * 128 + c];
    }
    red[h][ci] = s;
    __syncthreads();
    if (h == 0)
        part[bi * 128 + c] = red[0][ci] + red[1][ci] + red[2][ci] + red[3][ci];
}

// ---------------- Kernel 3: per-row loss + reduce + last-block finalize ------
__global__ __launch_bounds__(256) void loss_kernel(
    const float* __restrict__ part, const float* __restrict__ diag20,
    float* __restrict__ lacc, unsigned* __restrict__ cnt, float* __restrict__ out) {
    int i = blockIdx.x * 256 + threadIdx.x;
    float v = logf(part[i] + part[N + i]) - diag20[i];
    #pragma unroll
    for (int off = 32; off > 0; off >>= 1) v += __shfl_down(v, off, 64);
    __shared__ float wsm[4];
    int lane = threadIdx.x & 63, wv = threadIdx.x >> 6;
    if (lane == 0) wsm[wv] = v;
    __syncthreads();
    if (threadIdx.x == 0) {
        atomicAdd(lacc, wsm[0] + wsm[1] + wsm[2] + wsm[3]);
        __threadfence();
        unsigned old = atomicAdd(cnt, 1u);
        if (old == (N / 256 - 1)) {
            float tot = atomicAdd(lacc, 0.0f);
            out[0] = tot * (1.0f / (float)N);
        }
    }
}

// ---------------- launch ----------------
extern "C" void kernel_launch(void* const* d_in, const int* in_sizes, int n_in,
                              void* d_out, int out_size, void* d_ws, size_t ws_size,
                              hipStream_t stream) {
    const float* A = (const float*)d_in[0];
    const float* P = (const float*)d_in[1];

    __hip_bfloat16* Zn = (__hip_bfloat16*)d_ws;                 // 2N*64 bf16 = 2 MiB
    float* diag20 = (float*)((char*)d_ws + 2u * N * D * sizeof(__hip_bfloat16));
    float* rowbuf = diag20 + N;                 // NTILES*128 floats = 4.2 MB
    float* colbuf = rowbuf + NTILES * 128;      // NTILES*128 floats (adjacent!)
    float* part   = colbuf + NTILES * 128;      // 2N floats
    float* lacc   = part + 2 * N;
    unsigned* cnt = (unsigned*)(lacc + 1);

    prep_kernel<<<N / 4, 256, 0, stream>>>(A, P, Zn, diag20, lacc, cnt);

    tiles_kernel<<<NTILES / 2, 256, 0, stream>>>(Zn, rowbuf, colbuf);

    reduce_kernel<<<256, 256, 0, stream>>>(rowbuf, part);

    loss_kernel<<<N / 256, 256, 0, stream>>>(part, diag20, lacc, cnt, (float*)d_out);
}

// Round 6
// 98.165 us; speedup vs baseline: 1.5301x; 1.0300x over previous
//
#include <hip/hip_runtime.h>
#include <hip/hip_bf16.h>
#include <math.h>

#define N 8192
#define D 64
#define INVT 20.0f
#define EPS 1e-6f
// sqrt(20/ln2): gram(Z) = 20*log2(e)*cos, so exp2(gram) = e^{20 cos}
#define ZSCALE 5.3715835f

typedef __attribute__((ext_vector_type(8))) short bf16x8;
typedef __attribute__((ext_vector_type(4))) float f32x4;

#if __has_builtin(__builtin_amdgcn_exp2f)
#define EXP2F(x) __builtin_amdgcn_exp2f(x)
#else
#define EXP2F(x) exp2f(x)
#endif

// Z layout (fragment order): G-row R, element l stored at bf16 index
//   ( (R>>4)*128 + (l>>5)*64 + ((l>>3)&3)*16 + (R&15) )*8 + (l&7)
// MFMA fragment load for 16-row group g, K-chunk kc = contiguous 1 KB wave
// load Zf[g*128 + kc*64 + lane].
//
// HISTORY (keep):
//  - R9/R12: (256,5) spills. (256,4) is the occupancy ceiling.
//  - R10: __threadfence in all blocks -> L2 thrash, 5x slower.
//  - R11 (93.1us): 1 tile/block. R13 (91.8us): 2 ranks/block + prefetch.
//  - R14/R15 (112/117us): strip-mining defeated compiler pipelining.
//  - R16 (150us): 4-tile full unroll -> register overrun spill. ABANDONED.
//  - R17 (107.5us): atomics -> rowbuf/colbuf stores + gather kernel. Gather
//    was 64-block latency-bound (~12us).
//  - R18 (101.1us): gather fixed (256 blocks, ~3us), barrier-move + af1-reuse
//    validated. NET LESSON: stores+reduce round-trip (8.4MB W + RFO + 8.4MB R
//    + extra launch) is ~5-8us WORSE than R13's atomics. Atomic ping-pong
//    largely overlaps compute; the round-trip does not. Atomics WIN.
//  - R19 (this): R13 atomic structure + af1-reuse + barrier-move + XCD-aware
//    rank swizzle: wgid=(b&7)*516+(b>>3) (4128=8*516, bijective). Default
//    b%8 XCD round-robin scatters same-bi ranks across all 8 non-coherent
//    L2s; the swizzle gives each XCD a contiguous bi-band so row-atomic
//    lines stay in one L2.

__device__ __forceinline__ void unrank(int t, int& bi, int& bj) {
    int b = (int)((257.0f - sqrtf(66049.0f - 8.0f * (float)t)) * 0.5f);
    while (b * (257 - b) / 2 > t) --b;
    while ((b + 1) * (256 - b) / 2 <= t) ++b;
    bi = b;
    bj = b + (t - b * (257 - b) / 2);
}

// ---------------- Kernel 1: normalize -> scaled bf16 Z (fragment order),
//                  zero part[] / lacc / cnt ----------------
__global__ __launch_bounds__(256) void prep_kernel(
    const float* __restrict__ A, const float* __restrict__ P,
    __hip_bfloat16* __restrict__ Zn, float* __restrict__ diag20,
    float* __restrict__ part, float* __restrict__ lacc, unsigned* __restrict__ cnt) {
    if (blockIdx.x < 64) part[blockIdx.x * 256 + threadIdx.x] = 0.0f;
    else if (blockIdx.x == 64 && threadIdx.x == 0) { *lacc = 0.0f; *cnt = 0u; }

    const int lane = threadIdx.x & 63;   // element index l
    const int w    = threadIdx.x >> 6;
    const int r    = blockIdx.x * 4 + w; // A/P row
    const int u    = lane >> 3, sub = lane & 7;
    const int upos = (u >> 2) * 64 + (u & 3) * 16;   // kc*64 + q*16

    float a = A[r * D + lane];
    float p = P[r * D + lane];
    float sa = a * a, sp = p * p, dp = a * p;
    #pragma unroll
    for (int off = 1; off < 64; off <<= 1) {
        sa += __shfl_xor(sa, off, 64);
        sp += __shfl_xor(sp, off, 64);
        dp += __shfl_xor(dp, off, 64);
    }
    float na  = sqrtf(sa);
    float npn = sqrtf(sp);
    {   // A-row R = r
        int g = r >> 4, l2 = r & 15;
        Zn[(g * 128 + upos + l2) * 8 + sub] = __float2bfloat16(a * (ZSCALE / na));
    }
    {   // P-row R = N + r
        int R = N + r; int g = R >> 4, l2 = R & 15;
        Zn[(g * 128 + upos + l2) * 8 + sub] = __float2bfloat16(p * (ZSCALE / npn));
    }
    if (lane == 0)
        diag20[r] = (dp / fmaxf(na * npn, EPS)) * INVT;
}

// ---------------- Kernel 2: two triangular ranks per block, prefetched ------
__global__ __launch_bounds__(256, 4) void tiles_kernel(
    const __hip_bfloat16* __restrict__ Zn, float* __restrict__ part) {
    __shared__ float rs[4][16][68];     // wave-local transpose; 2-way banks max
    __shared__ float merged[2][128];    // row merge over wc
    __shared__ float cmerged[2][2][64]; // col merge over wr: [wr][wc][col]

    const int tid = threadIdx.x;
    const int lane = tid & 63, w = tid >> 6;
    const int wr = w >> 1, wc = w & 1;
    const int ln = lane & 15, q = lane >> 4;
    const bf16x8* Zf = (const bf16x8*)Zn;

    // XCD-aware swizzle: 4128 blocks = 8 XCDs x 516. Default XCD = b%8, so
    // give XCD x the contiguous wgid band [x*516,(x+1)*516) -> contiguous
    // bi band -> row-atomic lines stay in one XCD L2.
    const int b = (int)blockIdx.x;
    const int wgid = (b & 7) * 516 + (b >> 3);
    const int t0 = 2 * wgid;
    const int t1 = t0 + 1;
    int bi0, bj0, bi1, bj1;
    unrank(t0, bi0, bj0);
    unrank(t1, bi1, bj1);

    const f32x4 zero = {0.0f, 0.0f, 0.0f, 0.0f};

    // ---------------- tile 0: load fragments ----------------
    bf16x8 af0[4][2], bv0[4][2];
    #pragma unroll
    for (int ii = 0; ii < 4; ++ii) {
        int ga = bi0 * 8 + wr * 4 + ii;
        int gb = bj0 * 8 + wc * 4 + ii;
        #pragma unroll
        for (int kc = 0; kc < 2; ++kc) {
            af0[ii][kc] = Zf[ga * 128 + kc * 64 + lane];
            bv0[ii][kc] = Zf[gb * 128 + kc * 64 + lane];
        }
    }

    // ---------------- tile 0: stripes (MFMA + exp) ----------------
    const bool dwave0 = (bi0 == bj0) && (wr == wc);
    float csum[4] = {0.0f, 0.0f, 0.0f, 0.0f};
    #pragma unroll
    for (int ii = 0; ii < 4; ++ii) {
        f32x4 acc[4];
        #pragma unroll
        for (int jj = 0; jj < 4; ++jj)
            acc[jj] = __builtin_amdgcn_mfma_f32_16x16x32_bf16(
                af0[ii][0], bv0[jj][0], zero, 0, 0, 0);
        #pragma unroll
        for (int jj = 0; jj < 4; ++jj)
            acc[jj] = __builtin_amdgcn_mfma_f32_16x16x32_bf16(
                af0[ii][1], bv0[jj][1], acc[jj], 0, 0, 0);

        f32x4 rsum_ii = {};
        #pragma unroll
        for (int jj = 0; jj < 4; ++jj) {
            f32x4 e;
            #pragma unroll
            for (int r = 0; r < 4; ++r) e[r] = EXP2F(acc[jj][r]);
            if (dwave0 && (ii == jj)) {
                #pragma unroll
                for (int r = 0; r < 4; ++r)
                    if (ln == q * 4 + r) e[r] = 0.0f;
            }
            rsum_ii += e;
            csum[jj] += (e[0] + e[1]) + (e[2] + e[3]);
        }
        *(f32x4*)&rs[w][ln][ii * 16 + q * 4] = rsum_ii;
    }

    // ---------------- prefetch tile 1 fragments ----------------
    // af reused when the pair stays in the same row block (4064/4128 pairs).
    bf16x8 af1[4][2], bv1[4][2];
    #pragma unroll
    for (int ii = 0; ii < 4; ++ii) {
        int gb = bj1 * 8 + wc * 4 + ii;
        #pragma unroll
        for (int kc = 0; kc < 2; ++kc)
            bv1[ii][kc] = Zf[gb * 128 + kc * 64 + lane];
    }
    if (bi1 == bi0) {
        #pragma unroll
        for (int ii = 0; ii < 4; ++ii) {
            af1[ii][0] = af0[ii][0];
            af1[ii][1] = af0[ii][1];
        }
    } else {
        #pragma unroll
        for (int ii = 0; ii < 4; ++ii) {
            int ga = bi1 * 8 + wr * 4 + ii;
            #pragma unroll
            for (int kc = 0; kc < 2; ++kc)
                af1[ii][kc] = Zf[ga * 128 + kc * 64 + lane];
        }
    }

    // ---------------- tile 0: reductions + atomics ----------------
    {
        float rowsum = 0.0f;
        #pragma unroll
        for (int l = 0; l < 16; ++l) rowsum += rs[w][l][lane];
        merged[wc][wr * 64 + lane] = rowsum;

        float cs0 = csum[0], cs1 = csum[1], cs2 = csum[2], cs3 = csum[3];
        cs0 += __shfl_xor(cs0, 16, 64); cs0 += __shfl_xor(cs0, 32, 64);
        cs1 += __shfl_xor(cs1, 16, 64); cs1 += __shfl_xor(cs1, 32, 64);
        cs2 += __shfl_xor(cs2, 16, 64); cs2 += __shfl_xor(cs2, 32, 64);
        cs3 += __shfl_xor(cs3, 16, 64); cs3 += __shfl_xor(cs3, 32, 64);
        float cval = (q == 0) ? cs0 : (q == 1) ? cs1 : (q == 2) ? cs2 : cs3;
        cmerged[wr][wc][q * 16 + ln] = cval;
        __syncthreads();

        if (tid < 128) {
            atomicAdd(part + bi0 * 128 + tid, merged[0][tid] + merged[1][tid]);
        } else if (bi0 != bj0) {
            int col = tid - 128;
            atomicAdd(part + bj0 * 128 + col,
                      cmerged[0][col >> 6][col & 63] + cmerged[1][col >> 6][col & 63]);
        }
    }
    // No barrier here (validated R18): tile-1 stripes only write per-wave
    // rs[w], so tile-0's merged/cmerged reads + atomics overlap the next
    // MFMA/exp phase. Barrier moved to after tile-1 stripes.

    // ---------------- tile 1: stripes (MFMA + exp) ----------------
    const bool dwave1 = (bi1 == bj1) && (wr == wc);
    float csumB[4] = {0.0f, 0.0f, 0.0f, 0.0f};
    #pragma unroll
    for (int ii = 0; ii < 4; ++ii) {
        f32x4 acc[4];
        #pragma unroll
        for (int jj = 0; jj < 4; ++jj)
            acc[jj] = __builtin_amdgcn_mfma_f32_16x16x32_bf16(
                af1[ii][0], bv1[jj][0], zero, 0, 0, 0);
        #pragma unroll
        for (int jj = 0; jj < 4; ++jj)
            acc[jj] = __builtin_amdgcn_mfma_f32_16x16x32_bf16(
                af1[ii][1], bv1[jj][1], acc[jj], 0, 0, 0);

        f32x4 rsum_ii = {};
        #pragma unroll
        for (int jj = 0; jj < 4; ++jj) {
            f32x4 e;
            #pragma unroll
            for (int r = 0; r < 4; ++r) e[r] = EXP2F(acc[jj][r]);
            if (dwave1 && (ii == jj)) {
                #pragma unroll
                for (int r = 0; r < 4; ++r)
                    if (ln == q * 4 + r) e[r] = 0.0f;
            }
            rsum_ii += e;
            csumB[jj] += (e[0] + e[1]) + (e[2] + e[3]);
        }
        *(f32x4*)&rs[w][ln][ii * 16 + q * 4] = rsum_ii;
    }

    __syncthreads();   // tile-0 merged/cmerged reads are done; safe to rewrite

    // ---------------- tile 1: reductions + atomics ----------------
    {
        float rowsum = 0.0f;
        #pragma unroll
        for (int l = 0; l < 16; ++l) rowsum += rs[w][l][lane];
        merged[wc][wr * 64 + lane] = rowsum;

        float cs0 = csumB[0], cs1 = csumB[1], cs2 = csumB[2], cs3 = csumB[3];
        cs0 += __shfl_xor(cs0, 16, 64); cs0 += __shfl_xor(cs0, 32, 64);
        cs1 += __shfl_xor(cs1, 16, 64); cs1 += __shfl_xor(cs1, 32, 64);
        cs2 += __shfl_xor(cs2, 16, 64); cs2 += __shfl_xor(cs2, 32, 64);
        cs3 += __shfl_xor(cs3, 16, 64); cs3 += __shfl_xor(cs3, 32, 64);
        float cval = (q == 0) ? cs0 : (q == 1) ? cs1 : (q == 2) ? cs2 : cs3;
        cmerged[wr][wc][q * 16 + ln] = cval;
        __syncthreads();

        if (tid < 128) {
            atomicAdd(part + bi1 * 128 + tid, merged[0][tid] + merged[1][tid]);
        } else if (bi1 != bj1) {
            int col = tid - 128;
            atomicAdd(part + bj1 * 128 + col,
                      cmerged[0][col >> 6][col & 63] + cmerged[1][col >> 6][col & 63]);
        }
    }
}

// ---------------- Kernel 3: per-row loss + reduce + last-block finalize ------
__global__ __launch_bounds__(256) void loss_kernel(
    const float* __restrict__ part, const float* __restrict__ diag20,
    float* __restrict__ lacc, unsigned* __restrict__ cnt, float* __restrict__ out) {
    int i = blockIdx.x * 256 + threadIdx.x;
    float v = logf(part[i] + part[N + i]) - diag20[i];
    #pragma unroll
    for (int off = 32; off > 0; off >>= 1) v += __shfl_down(v, off, 64);
    __shared__ float wsm[4];
    int lane = threadIdx.x & 63, wv = threadIdx.x >> 6;
    if (lane == 0) wsm[wv] = v;
    __syncthreads();
    if (threadIdx.x == 0) {
        atomicAdd(lacc, wsm[0] + wsm[1] + wsm[2] + wsm[3]);
        __threadfence();
        unsigned old = atomicAdd(cnt, 1u);
        if (old == (N / 256 - 1)) {
            float tot = atomicAdd(lacc, 0.0f);
            out[0] = tot * (1.0f / (float)N);
        }
    }
}

// ---------------- launch ----------------
extern "C" void kernel_launch(void* const* d_in, const int* in_sizes, int n_in,
                              void* d_out, int out_size, void* d_ws, size_t ws_size,
                              hipStream_t stream) {
    const float* A = (const float*)d_in[0];
    const float* P = (const float*)d_in[1];

    __hip_bfloat16* Zn = (__hip_bfloat16*)d_ws;                 // 2N*64 bf16 = 2 MiB
    float* diag20 = (float*)((char*)d_ws + 2u * N * D * sizeof(__hip_bfloat16));
    float* part   = diag20 + N;          // 2N floats, atomic-accumulated
    float* lacc   = part + 2 * N;
    unsigned* cnt = (unsigned*)(lacc + 1);

    prep_kernel<<<N / 4, 256, 0, stream>>>(A, P, Zn, diag20, part, lacc, cnt);

    const int nblocks = 128 * 129 / 4;   // 4128 blocks, 2 triangular ranks each
    tiles_kernel<<<nblocks, 256, 0, stream>>>(Zn, part);

    loss_kernel<<<N / 256, 256, 0, stream>>>(part, diag20, lacc, cnt, (float*)d_out);
}